// Round 1
// baseline (6399.262 us; speedup 1.0000x reference)
//
#include <hip/hip_runtime.h>
#include <cstdint>
#include <cstddef>

#define NNODES 100000
#define NEDGES 1600000
#define NGRAPHS 64
#define HIDDIM 128
#define NCLS 8

// ---------------- degree / norm ----------------

__global__ void k_init_deg(float* deg, int n) {
    int i = blockIdx.x * blockDim.x + threadIdx.x;
    if (i < n) deg[i] = 1.0f;   // self-loop
}

__global__ void k_edge_deg(const int* __restrict__ dst, float* deg, int E) {
    int e = blockIdx.x * blockDim.x + threadIdx.x;
    if (e < E) atomicAdd(&deg[dst[e]], 1.0f);
}

__global__ void k_dinv(const float* __restrict__ deg, float* __restrict__ dinv, int n) {
    int i = blockIdx.x * blockDim.x + threadIdx.x;
    if (i < n) dinv[i] = rsqrtf(deg[i]);   // deg >= 1 always
}

// ---------------- GEMM: Y[n,128] = X[n,128] @ W[128,128] ----------------
// 32-row tile per block, K split into two 64-phases (LDS 40KB static).
// 256 threads: tx=tid&31 -> cols 4*tx..4*tx+3 ; ty=tid>>5 -> rows 4*ty..4*ty+3.

__global__ __launch_bounds__(256) void k_gemm128(const float* __restrict__ X,
                                                 const float* __restrict__ W,
                                                 float* __restrict__ Y, int nrows) {
    __shared__ float sW[64 * 128];
    __shared__ float sX[32 * 64];
    const int row0 = blockIdx.x * 32;
    const int tid = threadIdx.x;
    const int tx = tid & 31;
    const int ty = tid >> 5;
    float acc[4][4] = {};

    for (int kt = 0; kt < 128; kt += 64) {
        // stage W rows kt..kt+63 (2048 float4)
        for (int v = tid; v < 64 * 32; v += 256) {
            int kr = v >> 5, c4 = v & 31;
            ((float4*)sW)[v] = ((const float4*)(W + (size_t)(kt + kr) * 128))[c4];
        }
        // stage X rows row0..row0+31, cols kt..kt+63 (512 float4)
        for (int v = tid; v < 32 * 16; v += 256) {
            int r = v >> 4, c4 = v & 15;
            int row = row0 + r;
            float4 val = make_float4(0.f, 0.f, 0.f, 0.f);
            if (row < nrows)
                val = ((const float4*)(X + (size_t)row * 128 + kt))[c4];
            ((float4*)sX)[v] = val;
        }
        __syncthreads();
        #pragma unroll 8
        for (int k = 0; k < 64; ++k) {
            float4 w = ((const float4*)sW)[k * 32 + tx];
            #pragma unroll
            for (int i = 0; i < 4; ++i) {
                float xv = sX[(ty * 4 + i) * 64 + k];
                acc[i][0] += xv * w.x;
                acc[i][1] += xv * w.y;
                acc[i][2] += xv * w.z;
                acc[i][3] += xv * w.w;
            }
        }
        __syncthreads();
    }
    #pragma unroll
    for (int i = 0; i < 4; ++i) {
        int row = row0 + ty * 4 + i;
        if (row < nrows) {
            float4 o = make_float4(acc[i][0], acc[i][1], acc[i][2], acc[i][3]);
            ((float4*)(Y + (size_t)row * 128))[tx] = o;
        }
    }
}

// ---------------- self-loop init: out[i,:] = xw[i,:] * dinv[i]^2 ----------------

__global__ void k_selfloop(const float4* __restrict__ xw, const float* __restrict__ dinv,
                           float4* __restrict__ out, int n32) {
    int idx = blockIdx.x * blockDim.x + threadIdx.x;
    if (idx < n32) {
        int i = idx >> 5;
        float d = dinv[i];
        float s = d * d;
        float4 v = xw[idx];
        out[idx] = make_float4(v.x * s, v.y * s, v.z * s, v.w * s);
    }
}

// ---------------- edge aggregation: out[dst,:] += xw[src,:] * dinv[src]*dinv[dst] ----------------
// 32 lanes per edge, float4 gather + 4 scalar f32 atomics per lane.

__global__ __launch_bounds__(256) void k_edge_agg(const float4* __restrict__ xw,
                                                  const float* __restrict__ dinv,
                                                  const int* __restrict__ src,
                                                  const int* __restrict__ dst,
                                                  float* __restrict__ out, int E) {
    long long tid = (long long)blockIdx.x * blockDim.x + threadIdx.x;
    int lane = (int)(tid & 31);
    long long e = tid >> 5;
    if (e < E) {
        int s = src[e];
        int d = dst[e];
        float nrm = dinv[s] * dinv[d];
        float4 v = xw[(size_t)s * 32 + lane];
        float* o = out + (size_t)d * 128 + lane * 4;
        atomicAdd(o + 0, v.x * nrm);
        atomicAdd(o + 1, v.y * nrm);
        atomicAdd(o + 2, v.z * nrm);
        atomicAdd(o + 3, v.w * nrm);
    }
}

// ---------------- bias + relu (in place) ----------------

__global__ void k_bias_relu(float* __restrict__ buf, const float* __restrict__ b, int total) {
    int idx = blockIdx.x * blockDim.x + threadIdx.x;
    if (idx < total) {
        float v = buf[idx] + b[idx & 127];
        buf[idx] = v > 0.f ? v : 0.f;
    }
}

// ---------------- pooling ----------------

__global__ void k_zero(float* p, int n) {
    int i = blockIdx.x * blockDim.x + threadIdx.x;
    if (i < n) p[i] = 0.f;
}

__global__ void k_pool(const float* __restrict__ buf, const int* __restrict__ batch,
                       float* __restrict__ sums, int total) {
    int idx = blockIdx.x * blockDim.x + threadIdx.x;
    if (idx < total) {
        int i = idx >> 7;
        int c = idx & 127;
        atomicAdd(&sums[(size_t)batch[i] * 128 + c], buf[idx]);
    }
}

__global__ void k_count(const int* __restrict__ batch, float* __restrict__ counts, int n) {
    int i = blockIdx.x * blockDim.x + threadIdx.x;
    if (i < n) atomicAdd(&counts[batch[i]], 1.0f);
}

// out[g,k] = sum_c (sums[g,c]/cnt[g] + b2[c]) * linW[c,k] + linb[k]
__global__ void k_final(const float* __restrict__ sums, const float* __restrict__ counts,
                        const float* __restrict__ b2, const float* __restrict__ linW,
                        const float* __restrict__ linb, float* __restrict__ out) {
    int tid = threadIdx.x;           // 512 = 64 graphs * 8 classes
    int g = tid >> 3, k = tid & 7;
    float inv = 1.0f / fmaxf(counts[g], 1.0f);
    float acc = 0.f;
    for (int c = 0; c < 128; ++c)
        acc += (sums[(size_t)g * 128 + c] * inv + b2[c]) * linW[(size_t)c * 8 + k];
    out[(size_t)g * 8 + k] = acc + linb[k];
}

// ---------------- launch ----------------

extern "C" void kernel_launch(void* const* d_in, const int* in_sizes, int n_in,
                              void* d_out, int out_size, void* d_ws, size_t ws_size,
                              hipStream_t stream) {
    const float* x    = (const float*)d_in[0];
    const int*   ei   = (const int*)d_in[1];   // [2, E] row-major: src = ei, dst = ei+E
    const int*   batch= (const int*)d_in[2];
    const float* W1   = (const float*)d_in[3];
    const float* b1   = (const float*)d_in[4];
    const float* W2   = (const float*)d_in[5];
    const float* b2   = (const float*)d_in[6];
    const float* linW = (const float*)d_in[7];
    const float* linb = (const float*)d_in[8];
    float* out = (float*)d_out;

    const int N = NNODES, E = NEDGES;
    const int* src = ei;
    const int* dst = ei + E;

    float* ws = (float*)d_ws;
    float* bufA  = ws;                       // [N,128]
    float* bufB  = ws + (size_t)N * 128;     // [N,128]
    float* deg   = bufB + (size_t)N * 128;   // [N]
    float* dinv  = deg + N;                  // [N]
    float* sums  = dinv + N;                 // [64,128]
    float* cnts  = sums + NGRAPHS * 128;     // [64]

    const int B = 256;
    dim3 blk(B);

    // norms
    k_init_deg<<<(N + B - 1) / B, blk, 0, stream>>>(deg, N);
    k_edge_deg<<<(E + B - 1) / B, blk, 0, stream>>>(dst, deg, E);
    k_dinv<<<(N + B - 1) / B, blk, 0, stream>>>(deg, dinv, N);

    const int gemmGrid = (N + 31) / 32;            // 3125
    const int n32 = N * 32;                        // float4 count
    const int tot = N * 128;
    const long long edgeThreads = (long long)E * 32;
    const int edgeGrid = (int)((edgeThreads + B - 1) / B);

    // ---- layer 1 ----
    k_gemm128<<<gemmGrid, blk, 0, stream>>>(x, W1, bufA, N);
    k_selfloop<<<(n32 + B - 1) / B, blk, 0, stream>>>((const float4*)bufA, dinv, (float4*)bufB, n32);
    k_edge_agg<<<edgeGrid, blk, 0, stream>>>((const float4*)bufA, dinv, src, dst, bufB, E);
    k_bias_relu<<<(tot + B - 1) / B, blk, 0, stream>>>(bufB, b1, tot);

    // ---- layer 2 ----
    k_gemm128<<<gemmGrid, blk, 0, stream>>>(bufB, W2, bufA, N);
    k_selfloop<<<(n32 + B - 1) / B, blk, 0, stream>>>((const float4*)bufA, dinv, (float4*)bufB, n32);
    k_edge_agg<<<edgeGrid, blk, 0, stream>>>((const float4*)bufA, dinv, src, dst, bufB, E);

    // ---- pool + head ----
    k_zero<<<(NGRAPHS * 128 + NGRAPHS + B - 1) / B, blk, 0, stream>>>(sums, NGRAPHS * 128 + NGRAPHS);
    k_pool<<<(tot + B - 1) / B, blk, 0, stream>>>(bufB, batch, sums, tot);
    k_count<<<(N + B - 1) / B, blk, 0, stream>>>(batch, cnts, N);
    k_final<<<1, 512, 0, stream>>>(sums, cnts, b2, linW, linb, out);
}

// Round 2
// 632.587 us; speedup vs baseline: 10.1160x; 10.1160x over previous
//
#include <hip/hip_runtime.h>
#include <cstdint>
#include <cstddef>

#define NNODES 100000
#define NEDGES 1600000
#define NGRAPHS 64
#define HIDDIM 128
#define NCLS 8

// ---------------- zero / degree / norm ----------------

__global__ void k_zero_int(int* p, int n) {
    int i = blockIdx.x * blockDim.x + threadIdx.x;
    if (i < n) p[i] = 0;
}

__global__ void k_count_dst(const int* __restrict__ dst, int* __restrict__ cnt, int E) {
    int e = blockIdx.x * blockDim.x + threadIdx.x;
    if (e < E) atomicAdd(&cnt[dst[e]], 1);
}

__global__ void k_dinv(const int* __restrict__ cnt, float* __restrict__ dinv, int n) {
    int i = blockIdx.x * blockDim.x + threadIdx.x;
    if (i < n) dinv[i] = rsqrtf((float)(cnt[i] + 1));  // +1 self-loop, always >=1
}

// ---------------- exclusive scan (hierarchical, 1024 elems/block) ----------------

__global__ __launch_bounds__(256) void k_scan_local(const int* __restrict__ cnt,
                                                    int* __restrict__ offs,
                                                    int* __restrict__ bsums, int n) {
    __shared__ int sh[256];
    int t = threadIdx.x;
    int base = blockIdx.x * 1024 + t * 4;
    int v0 = base + 0 < n ? cnt[base + 0] : 0;
    int v1 = base + 1 < n ? cnt[base + 1] : 0;
    int v2 = base + 2 < n ? cnt[base + 2] : 0;
    int v3 = base + 3 < n ? cnt[base + 3] : 0;
    int tsum = v0 + v1 + v2 + v3;
    sh[t] = tsum;
    __syncthreads();
    #pragma unroll
    for (int d = 1; d < 256; d <<= 1) {
        int val = (t >= d) ? sh[t - d] : 0;
        __syncthreads();
        sh[t] += val;
        __syncthreads();
    }
    int excl = sh[t] - tsum;
    if (t == 255) bsums[blockIdx.x] = sh[255];
    if (base + 0 < n) offs[base + 0] = excl;
    if (base + 1 < n) offs[base + 1] = excl + v0;
    if (base + 2 < n) offs[base + 2] = excl + v0 + v1;
    if (base + 3 < n) offs[base + 3] = excl + v0 + v1 + v2;
}

__global__ __launch_bounds__(256) void k_scan_bsums(int* bsums, int nb) {
    __shared__ int sh[256];
    int t = threadIdx.x;
    int v = t < nb ? bsums[t] : 0;
    sh[t] = v;
    __syncthreads();
    #pragma unroll
    for (int d = 1; d < 256; d <<= 1) {
        int val = (t >= d) ? sh[t - d] : 0;
        __syncthreads();
        sh[t] += val;
        __syncthreads();
    }
    if (t < nb) bsums[t] = sh[t] - v;  // exclusive
}

__global__ void k_scan_add(int* __restrict__ offs, int* __restrict__ cursor,
                           const int* __restrict__ bsums, int n) {
    int i = blockIdx.x * blockDim.x + threadIdx.x;
    if (i < n) {
        int v = offs[i] + bsums[i >> 10];
        offs[i] = v;
        cursor[i] = v;
    }
    if (i == 0) offs[n] = NEDGES;
}

// ---------------- CSR scatter ----------------

__global__ void k_scatter(const int* __restrict__ src, const int* __restrict__ dst,
                          int* __restrict__ cursor, int* __restrict__ csr, int E) {
    int e = blockIdx.x * blockDim.x + threadIdx.x;
    if (e < E) {
        int d = dst[e];
        int pos = atomicAdd(&cursor[d], 1);
        csr[pos] = src[e];
    }
}

// ---------------- GEMM: Y[n,128] = X[n,128] @ W[128,128] ----------------

__global__ __launch_bounds__(256) void k_gemm128(const float* __restrict__ X,
                                                 const float* __restrict__ W,
                                                 float* __restrict__ Y, int nrows) {
    __shared__ float sW[64 * 128];
    __shared__ float sX[32 * 64];
    const int row0 = blockIdx.x * 32;
    const int tid = threadIdx.x;
    const int tx = tid & 31;
    const int ty = tid >> 5;
    float acc[4][4] = {};

    for (int kt = 0; kt < 128; kt += 64) {
        for (int v = tid; v < 64 * 32; v += 256) {
            int kr = v >> 5, c4 = v & 31;
            ((float4*)sW)[v] = ((const float4*)(W + (size_t)(kt + kr) * 128))[c4];
        }
        for (int v = tid; v < 32 * 16; v += 256) {
            int r = v >> 4, c4 = v & 15;
            int row = row0 + r;
            float4 val = make_float4(0.f, 0.f, 0.f, 0.f);
            if (row < nrows)
                val = ((const float4*)(X + (size_t)row * 128 + kt))[c4];
            ((float4*)sX)[v] = val;
        }
        __syncthreads();
        #pragma unroll 8
        for (int k = 0; k < 64; ++k) {
            float4 w = ((const float4*)sW)[k * 32 + tx];
            #pragma unroll
            for (int i = 0; i < 4; ++i) {
                float xv = sX[(ty * 4 + i) * 64 + k];
                acc[i][0] += xv * w.x;
                acc[i][1] += xv * w.y;
                acc[i][2] += xv * w.z;
                acc[i][3] += xv * w.w;
            }
        }
        __syncthreads();
    }
    #pragma unroll
    for (int i = 0; i < 4; ++i) {
        int row = row0 + ty * 4 + i;
        if (row < nrows) {
            float4 o = make_float4(acc[i][0], acc[i][1], acc[i][2], acc[i][3]);
            ((float4*)(Y + (size_t)row * 128))[tx] = o;
        }
    }
}

// ---------------- CSR aggregation: one wave per node ----------------
// out[i,:] = sum_{s in in(i)} xw[s,:]*dinv[s]*dinv[i] + xw[i,:]*dinv[i]^2 (+bias,relu)

__global__ __launch_bounds__(256) void k_agg_csr(const float2* __restrict__ xw,
                                                 const float* __restrict__ dinv,
                                                 const int* __restrict__ offs,
                                                 const int* __restrict__ csr,
                                                 const float* __restrict__ bias,
                                                 float* __restrict__ out, int n, int dorelu) {
    int wid = (int)((blockIdx.x * 256 + threadIdx.x) >> 6);
    int lane = threadIdx.x & 63;
    if (wid >= n) return;
    float dd = dinv[wid];
    float2 v = xw[(size_t)wid * 64 + lane];
    float sl = dd * dd;
    float ax = v.x * sl, ay = v.y * sl;
    int e0 = offs[wid], e1 = offs[wid + 1];
    for (int e = e0; e < e1; e += 64) {
        int me = e + lane;
        int sidx = 0;
        float nr = 0.f;
        if (me < e1) {
            sidx = csr[me];
            nr = dinv[sidx] * dd;
        }
        int cnt = min(64, e1 - e);
        for (int k = 0; k < cnt; ++k) {
            int s = __shfl(sidx, k);
            float nm = __shfl(nr, k);
            float2 xv = xw[(size_t)s * 64 + lane];
            ax += xv.x * nm;
            ay += xv.y * nm;
        }
    }
    if (bias) {
        ax += bias[lane * 2];
        ay += bias[lane * 2 + 1];
        if (dorelu) {
            ax = fmaxf(ax, 0.f);
            ay = fmaxf(ay, 0.f);
        }
    }
    ((float2*)out)[(size_t)wid * 64 + lane] = make_float2(ax, ay);
}

// ---------------- pooling (batch is sorted -> segment bounds) ----------------

__global__ void k_bounds(const int* __restrict__ batch, int* __restrict__ start,
                         int* __restrict__ endx, int n) {
    int i = blockIdx.x * blockDim.x + threadIdx.x;
    if (i >= n) return;
    int b = batch[i];
    if (i == 0 || batch[i - 1] != b) start[b] = i;
    if (i == n - 1 || batch[i + 1] != b) endx[b] = i + 1;
}

__global__ __launch_bounds__(128) void k_pool_seg(const float* __restrict__ buf,
                                                  const int* __restrict__ start,
                                                  const int* __restrict__ endx,
                                                  float* __restrict__ sums) {
    int g = blockIdx.x;
    int chunk = blockIdx.y;  // 0..7
    int s = start[g], e = endx[g];
    int per = (e - s + 7) >> 3;
    int r0 = s + chunk * per;
    int r1 = min(e, r0 + per);
    int c = threadIdx.x;
    float acc = 0.f;
    for (int r = r0; r < r1; ++r) acc += buf[(size_t)r * 128 + c];
    atomicAdd(&sums[g * 128 + c], acc);
}

// out[g,k] = sum_c (sums[g,c]/cnt[g] + b2[c]) * linW[c,k] + linb[k]
__global__ void k_final(const float* __restrict__ sums, const int* __restrict__ start,
                        const int* __restrict__ endx, const float* __restrict__ b2,
                        const float* __restrict__ linW, const float* __restrict__ linb,
                        float* __restrict__ out) {
    int tid = threadIdx.x;  // 512 = 64 graphs * 8 classes
    int g = tid >> 3, k = tid & 7;
    float cnt = (float)(endx[g] - start[g]);
    float inv = 1.0f / fmaxf(cnt, 1.0f);
    float acc = 0.f;
    for (int c = 0; c < 128; ++c)
        acc += (sums[(size_t)g * 128 + c] * inv + b2[c]) * linW[(size_t)c * 8 + k];
    out[(size_t)g * 8 + k] = acc + linb[k];
}

// ---------------- launch ----------------

extern "C" void kernel_launch(void* const* d_in, const int* in_sizes, int n_in,
                              void* d_out, int out_size, void* d_ws, size_t ws_size,
                              hipStream_t stream) {
    const float* x     = (const float*)d_in[0];
    const int*   ei    = (const int*)d_in[1];  // [2,E]: src = ei, dst = ei+E
    const int*   batch = (const int*)d_in[2];
    const float* W1    = (const float*)d_in[3];
    const float* b1    = (const float*)d_in[4];
    const float* W2    = (const float*)d_in[5];
    const float* b2    = (const float*)d_in[6];
    const float* linW  = (const float*)d_in[7];
    const float* linb  = (const float*)d_in[8];
    float* out = (float*)d_out;

    const int N = NNODES, E = NEDGES;
    const int* src = ei;
    const int* dst = ei + E;

    char* ws = (char*)d_ws;
    float* bufA   = (float*)ws;                    ws += (size_t)N * 128 * 4;  // 51.2MB
    float* bufB   = (float*)ws;                    ws += (size_t)N * 128 * 4;  // 51.2MB
    float* dinv   = (float*)ws;                    ws += (size_t)N * 4;
    int*   cnt    = (int*)ws;                      ws += (size_t)N * 4;
    int*   offs   = (int*)ws;                      ws += (size_t)(N + 1) * 4;
    int*   cursor = (int*)ws;                      ws += (size_t)N * 4;
    int*   bsums  = (int*)ws;                      ws += 128 * 4;
    int*   csr    = (int*)ws;                      ws += (size_t)E * 4;        // 6.4MB
    float* sums   = (float*)ws;                    ws += NGRAPHS * 128 * 4;
    int*   gstart = (int*)ws;                      ws += NGRAPHS * 4;
    int*   gend   = (int*)ws;                      ws += NGRAPHS * 4;

    const int B = 256;
    const int nScanBlocks = (N + 1023) / 1024;  // 98

    // degree + norm
    k_zero_int<<<(N + B - 1) / B, B, 0, stream>>>(cnt, N);
    k_zero_int<<<(NGRAPHS * 128 + 2 * NGRAPHS + B - 1) / B, B, 0, stream>>>((int*)sums,
                                                                NGRAPHS * 128 + 2 * NGRAPHS);
    k_count_dst<<<(E + B - 1) / B, B, 0, stream>>>(dst, cnt, E);
    k_dinv<<<(N + B - 1) / B, B, 0, stream>>>(cnt, dinv, N);

    // CSR build
    k_scan_local<<<nScanBlocks, B, 0, stream>>>(cnt, offs, bsums, N);
    k_scan_bsums<<<1, B, 0, stream>>>(bsums, nScanBlocks);
    k_scan_add<<<(N + B - 1) / B, B, 0, stream>>>(offs, cursor, bsums, N);
    k_scatter<<<(E + B - 1) / B, B, 0, stream>>>(src, dst, cursor, csr, E);

    // graph segment bounds (batch sorted)
    k_bounds<<<(N + B - 1) / B, B, 0, stream>>>(batch, gstart, gend, N);

    const int gemmGrid = (N + 31) / 32;
    const int aggGrid = (N * 64 + B - 1) / B;  // one wave per node

    // layer 1
    k_gemm128<<<gemmGrid, B, 0, stream>>>(x, W1, bufA, N);
    k_agg_csr<<<aggGrid, B, 0, stream>>>((const float2*)bufA, dinv, offs, csr, b1, bufB, N, 1);

    // layer 2
    k_gemm128<<<gemmGrid, B, 0, stream>>>(bufB, W2, bufA, N);
    k_agg_csr<<<aggGrid, B, 0, stream>>>((const float2*)bufA, dinv, offs, csr, nullptr, bufB, N, 0);

    // pool + head
    k_pool_seg<<<dim3(NGRAPHS, 8), 128, 0, stream>>>(bufB, gstart, gend, sums);
    k_final<<<1, 512, 0, stream>>>(sums, gstart, gend, b2, linW, linb, out);
}

// Round 3
// 472.737 us; speedup vs baseline: 13.5366x; 1.3381x over previous
//
#include <hip/hip_runtime.h>
#include <cstdint>
#include <cstddef>

#define NNODES 100000
#define NEDGES 1600000
#define NGRAPHS 64

typedef short short8v __attribute__((ext_vector_type(8)));
typedef float float4v __attribute__((ext_vector_type(4)));

__device__ inline ushort f2bf(float f) {
    uint u = __float_as_uint(f);
    uint r = (u + 0x7fffu + ((u >> 16) & 1u)) >> 16;
    return (ushort)r;
}
__device__ inline float bflo(uint u) { return __uint_as_float(u << 16); }
__device__ inline float bfhi(uint u) { return __uint_as_float(u & 0xffff0000u); }

// ---------------- zero / degree / norm ----------------

__global__ void k_zero_int(int* p, int n) {
    int i = blockIdx.x * blockDim.x + threadIdx.x;
    if (i < n) p[i] = 0;
}

__global__ void k_count_dst(const int* __restrict__ dst, int* __restrict__ cnt, int E) {
    int e = blockIdx.x * blockDim.x + threadIdx.x;
    if (e < E) atomicAdd(&cnt[dst[e]], 1);
}

__global__ void k_dinv(const int* __restrict__ cnt, float* __restrict__ dinv, int n) {
    int i = blockIdx.x * blockDim.x + threadIdx.x;
    if (i < n) dinv[i] = rsqrtf((float)(cnt[i] + 1));  // +1 self-loop
}

// ---------------- exclusive scan ----------------

__global__ __launch_bounds__(256) void k_scan_local(const int* __restrict__ cnt,
                                                    int* __restrict__ offs,
                                                    int* __restrict__ bsums, int n) {
    __shared__ int sh[256];
    int t = threadIdx.x;
    int base = blockIdx.x * 1024 + t * 4;
    int v0 = base + 0 < n ? cnt[base + 0] : 0;
    int v1 = base + 1 < n ? cnt[base + 1] : 0;
    int v2 = base + 2 < n ? cnt[base + 2] : 0;
    int v3 = base + 3 < n ? cnt[base + 3] : 0;
    int tsum = v0 + v1 + v2 + v3;
    sh[t] = tsum;
    __syncthreads();
    #pragma unroll
    for (int d = 1; d < 256; d <<= 1) {
        int val = (t >= d) ? sh[t - d] : 0;
        __syncthreads();
        sh[t] += val;
        __syncthreads();
    }
    int excl = sh[t] - tsum;
    if (t == 255) bsums[blockIdx.x] = sh[255];
    if (base + 0 < n) offs[base + 0] = excl;
    if (base + 1 < n) offs[base + 1] = excl + v0;
    if (base + 2 < n) offs[base + 2] = excl + v0 + v1;
    if (base + 3 < n) offs[base + 3] = excl + v0 + v1 + v2;
}

__global__ __launch_bounds__(256) void k_scan_bsums(int* bsums, int nb) {
    __shared__ int sh[256];
    int t = threadIdx.x;
    int v = t < nb ? bsums[t] : 0;
    sh[t] = v;
    __syncthreads();
    #pragma unroll
    for (int d = 1; d < 256; d <<= 1) {
        int val = (t >= d) ? sh[t - d] : 0;
        __syncthreads();
        sh[t] += val;
        __syncthreads();
    }
    if (t < nb) bsums[t] = sh[t] - v;
}

__global__ void k_scan_add(int* __restrict__ offs, int* __restrict__ cursor,
                           const int* __restrict__ bsums, int n) {
    int i = blockIdx.x * blockDim.x + threadIdx.x;
    if (i < n) {
        int v = offs[i] + bsums[i >> 10];
        offs[i] = v;
        cursor[i] = v;
    }
    if (i == 0) offs[n] = NEDGES;
}

__global__ void k_scatter(const int* __restrict__ src, const int* __restrict__ dst,
                          int* __restrict__ cursor, int* __restrict__ csr, int E) {
    int e = blockIdx.x * blockDim.x + threadIdx.x;
    if (e < E) {
        int d = dst[e];
        int pos = atomicAdd(&cursor[d], 1);
        csr[pos] = src[e];
    }
}

// ---------------- MFMA GEMM: Y_bf16[n,128] = X_f32[n,128] @ W_f32[128,128] ----------------
// 4 waves/block, each wave does 16 rows x 128 cols. W staged in LDS in fragment order.

__global__ __launch_bounds__(256) void k_gemm_mfma(const float* __restrict__ X,
                                                   const float* __restrict__ W,
                                                   ushort* __restrict__ Y, int nrows) {
    __shared__ short8v sW[2048];  // [kk(4)][ct(8)][lane(64)] -> 8 bf16
    const int tid = threadIdx.x;
    const int lane = tid & 63;
    const int w = tid >> 6;

    for (int s = tid; s < 2048; s += 256) {
        int p = s >> 6, l = s & 63;
        int kk = p >> 3, ct = p & 7;
        int kb = kk * 32 + (l >> 4) * 8;
        int j = ct * 16 + (l & 15);
        short8v v;
        #pragma unroll
        for (int i = 0; i < 8; ++i)
            v[i] = (short)f2bf(W[(size_t)(kb + i) * 128 + j]);
        sW[s] = v;
    }
    __syncthreads();

    const int row0 = blockIdx.x * 64 + w * 16;
    const int arow = row0 + (lane & 15);
    float4v acc[8];
    #pragma unroll
    for (int ct = 0; ct < 8; ++ct) acc[ct] = (float4v)0.f;

    #pragma unroll
    for (int kk = 0; kk < 4; ++kk) {
        short8v a = (short8v)0;
        if (arow < nrows) {
            const float* xp = X + (size_t)arow * 128 + kk * 32 + ((lane >> 4) * 8);
            float4 f0 = ((const float4*)xp)[0];
            float4 f1 = ((const float4*)xp)[1];
            a[0] = (short)f2bf(f0.x); a[1] = (short)f2bf(f0.y);
            a[2] = (short)f2bf(f0.z); a[3] = (short)f2bf(f0.w);
            a[4] = (short)f2bf(f1.x); a[5] = (short)f2bf(f1.y);
            a[6] = (short)f2bf(f1.z); a[7] = (short)f2bf(f1.w);
        }
        #pragma unroll
        for (int ct = 0; ct < 8; ++ct)
            acc[ct] = __builtin_amdgcn_mfma_f32_16x16x32_bf16(a, sW[(kk * 8 + ct) * 64 + lane],
                                                              acc[ct], 0, 0, 0);
    }

    const int orow = row0 + ((lane >> 4) << 2);
    #pragma unroll
    for (int r = 0; r < 4; ++r) {
        int row = orow + r;
        if (row < nrows) {
            #pragma unroll
            for (int ct = 0; ct < 8; ++ct)
                Y[(size_t)row * 128 + ct * 16 + (lane & 15)] = f2bf(acc[ct][r]);
        }
    }
}

// ---------------- CSR aggregation on bf16 messages ----------------
// out[i,:] = sum_{s in in(i)} xw[s,:]*dinv[s]*dinv[i] + xw[i,:]*dinv[i]^2 (+bias,relu)

__global__ __launch_bounds__(256) void k_agg_bf16(const uint* __restrict__ xw,
                                                  const float* __restrict__ dinv,
                                                  const int* __restrict__ offs,
                                                  const int* __restrict__ csr,
                                                  const float* __restrict__ bias,
                                                  float2* __restrict__ out, int n, int dorelu) {
    int wid = (int)((blockIdx.x * 256 + threadIdx.x) >> 6);
    int lane = threadIdx.x & 63;
    if (wid >= n) return;
    float dd = dinv[wid];
    uint u = xw[(size_t)wid * 64 + lane];
    float sl = dd * dd;
    float ax = bflo(u) * sl, ay = bfhi(u) * sl;
    int e0 = offs[wid], e1 = offs[wid + 1];
    for (int e = e0; e < e1; e += 64) {
        int me = e + lane;
        int sidx = 0; float nr = 0.f;
        if (me < e1) { sidx = csr[me]; nr = dinv[sidx] * dd; }
        int cnt = min(64, e1 - e);
        int k = 0;
        for (; k + 2 <= cnt; k += 2) {
            int s0 = __shfl(sidx, k), s1 = __shfl(sidx, k + 1);
            float n0 = __shfl(nr, k), n1 = __shfl(nr, k + 1);
            uint u0 = xw[(size_t)s0 * 64 + lane];
            uint u1 = xw[(size_t)s1 * 64 + lane];
            ax += bflo(u0) * n0 + bflo(u1) * n1;
            ay += bfhi(u0) * n0 + bfhi(u1) * n1;
        }
        if (k < cnt) {
            int s0 = __shfl(sidx, k);
            float n0 = __shfl(nr, k);
            uint u0 = xw[(size_t)s0 * 64 + lane];
            ax += bflo(u0) * n0;
            ay += bfhi(u0) * n0;
        }
    }
    if (bias) {
        ax += bias[lane * 2];
        ay += bias[lane * 2 + 1];
        if (dorelu) { ax = fmaxf(ax, 0.f); ay = fmaxf(ay, 0.f); }
    }
    out[(size_t)wid * 64 + lane] = make_float2(ax, ay);
}

// ---------------- pooling ----------------

__global__ void k_bounds(const int* __restrict__ batch, int* __restrict__ start,
                         int* __restrict__ endx, int n) {
    int i = blockIdx.x * blockDim.x + threadIdx.x;
    if (i >= n) return;
    int b = batch[i];
    if (i == 0 || batch[i - 1] != b) start[b] = i;
    if (i == n - 1 || batch[i + 1] != b) endx[b] = i + 1;
}

__global__ __launch_bounds__(128) void k_pool_seg(const float* __restrict__ buf,
                                                  const int* __restrict__ start,
                                                  const int* __restrict__ endx,
                                                  float* __restrict__ sums) {
    int g = blockIdx.x;
    int chunk = blockIdx.y;
    int s = start[g], e = endx[g];
    int per = (e - s + 7) >> 3;
    int r0 = s + chunk * per;
    int r1 = min(e, r0 + per);
    int c = threadIdx.x;
    float acc = 0.f;
    for (int r = r0; r < r1; ++r) acc += buf[(size_t)r * 128 + c];
    atomicAdd(&sums[g * 128 + c], acc);
}

__global__ void k_final(const float* __restrict__ sums, const int* __restrict__ start,
                        const int* __restrict__ endx, const float* __restrict__ b2,
                        const float* __restrict__ linW, const float* __restrict__ linb,
                        float* __restrict__ out) {
    int tid = threadIdx.x;  // 512 = 64 graphs * 8 classes
    int g = tid >> 3, k = tid & 7;
    float cnt = (float)(endx[g] - start[g]);
    float inv = 1.0f / fmaxf(cnt, 1.0f);
    float acc = 0.f;
    for (int c = 0; c < 128; ++c)
        acc += (sums[(size_t)g * 128 + c] * inv + b2[c]) * linW[(size_t)c * 8 + k];
    out[(size_t)g * 8 + k] = acc + linb[k];
}

// ---------------- launch ----------------

extern "C" void kernel_launch(void* const* d_in, const int* in_sizes, int n_in,
                              void* d_out, int out_size, void* d_ws, size_t ws_size,
                              hipStream_t stream) {
    const float* x     = (const float*)d_in[0];
    const int*   ei    = (const int*)d_in[1];  // [2,E]: src = ei, dst = ei+E
    const int*   batch = (const int*)d_in[2];
    const float* W1    = (const float*)d_in[3];
    const float* b1    = (const float*)d_in[4];
    const float* W2    = (const float*)d_in[5];
    const float* b2    = (const float*)d_in[6];
    const float* linW  = (const float*)d_in[7];
    const float* linb  = (const float*)d_in[8];
    float* out = (float*)d_out;

    const int N = NNODES, E = NEDGES;
    const int* src = ei;
    const int* dst = ei + E;

    char* ws = (char*)d_ws;
    float* bufB   = (float*)ws;    ws += (size_t)N * 128 * 4;  // f32 hidden, 51.2MB
    uint*  bufA16 = (uint*)ws;     ws += (size_t)N * 64 * 4;   // bf16 xw, 25.6MB
    float* dinv   = (float*)ws;    ws += (size_t)N * 4;
    int*   cnt    = (int*)ws;      ws += (size_t)N * 4;
    int*   offs   = (int*)ws;      ws += (size_t)(N + 1) * 4;
    int*   cursor = (int*)ws;      ws += (size_t)N * 4;
    int*   bsums  = (int*)ws;      ws += 128 * 4;
    int*   csr    = (int*)ws;      ws += (size_t)E * 4;        // 6.4MB
    float* sums   = (float*)ws;    ws += NGRAPHS * 128 * 4;
    int*   gstart = (int*)ws;      ws += NGRAPHS * 4;
    int*   gend   = (int*)ws;      ws += NGRAPHS * 4;

    const int B = 256;
    const int nScanBlocks = (N + 1023) / 1024;

    k_zero_int<<<(N + B - 1) / B, B, 0, stream>>>(cnt, N);
    k_zero_int<<<(NGRAPHS * 128 + 2 * NGRAPHS + B - 1) / B, B, 0, stream>>>((int*)sums,
                                                            NGRAPHS * 128 + 2 * NGRAPHS);
    k_count_dst<<<(E + B - 1) / B, B, 0, stream>>>(dst, cnt, E);
    k_dinv<<<(N + B - 1) / B, B, 0, stream>>>(cnt, dinv, N);

    k_scan_local<<<nScanBlocks, B, 0, stream>>>(cnt, offs, bsums, N);
    k_scan_bsums<<<1, B, 0, stream>>>(bsums, nScanBlocks);
    k_scan_add<<<(N + B - 1) / B, B, 0, stream>>>(offs, cursor, bsums, N);
    k_scatter<<<(E + B - 1) / B, B, 0, stream>>>(src, dst, cursor, csr, E);

    k_bounds<<<(N + B - 1) / B, B, 0, stream>>>(batch, gstart, gend, N);

    const int gemmGrid = (N + 63) / 64;
    const int aggGrid = (N * 64 + B - 1) / B;

    // layer 1
    k_gemm_mfma<<<gemmGrid, B, 0, stream>>>(x, W1, (ushort*)bufA16, N);
    k_agg_bf16<<<aggGrid, B, 0, stream>>>(bufA16, dinv, offs, csr, b1, (float2*)bufB, N, 1);

    // layer 2
    k_gemm_mfma<<<gemmGrid, B, 0, stream>>>(bufB, W2, (ushort*)bufA16, N);
    k_agg_bf16<<<aggGrid, B, 0, stream>>>(bufA16, dinv, offs, csr, nullptr, (float2*)bufB, N, 0);

    // pool + head
    k_pool_seg<<<dim3(NGRAPHS, 8), 128, 0, stream>>>(bufB, gstart, gend, sums);
    k_final<<<1, 512, 0, stream>>>(sums, gstart, gend, b2, linW, linb, out);
}

// Round 4
// 355.765 us; speedup vs baseline: 17.9873x; 1.3288x over previous
//
#include <hip/hip_runtime.h>
#include <cstdint>
#include <cstddef>

#define NNODES 100000
#define NEDGES 1600000
#define NGRAPHS 64
#define BSHIFT 8
#define BRANGE 256
#define NB 391  // ceil(NNODES / 256)

typedef short short8v __attribute__((ext_vector_type(8)));
typedef float float4v __attribute__((ext_vector_type(4)));

__device__ inline ushort f2bf(float f) {
    uint u = __float_as_uint(f);
    uint r = (u + 0x7fffu + ((u >> 16) & 1u)) >> 16;
    return (ushort)r;
}
__device__ inline float bflo(uint u) { return __uint_as_float(u << 16); }
__device__ inline float bfhi(uint u) { return __uint_as_float(u & 0xffff0000u); }

// ---------------- small utils ----------------

__global__ void k_zero_int(int* p, int n) {
    int i = blockIdx.x * blockDim.x + threadIdx.x;
    if (i < n) p[i] = 0;
}

__global__ void k_dinv(const int* __restrict__ cnt, float* __restrict__ dinv, int n) {
    int i = blockIdx.x * blockDim.x + threadIdx.x;
    if (i < n) dinv[i] = rsqrtf((float)(cnt[i] + 1));  // +1 self-loop
}

// ---------------- CSR build: bucket phase ----------------

// P0: per-bucket edge counts (LDS histogram, ~100k global atomics)
__global__ __launch_bounds__(256) void k_bcount(const int* __restrict__ dst,
                                                int* __restrict__ bcnt, int E) {
    __shared__ int h[NB];
    for (int i = threadIdx.x; i < NB; i += 256) h[i] = 0;
    __syncthreads();
    for (int e = blockIdx.x * 256 + threadIdx.x; e < E; e += gridDim.x * 256)
        atomicAdd(&h[dst[e] >> BSHIFT], 1);
    __syncthreads();
    for (int i = threadIdx.x; i < NB; i += 256)
        if (h[i]) atomicAdd(&bcnt[i], h[i]);
}

// scan of 391 bucket counts -> boffs, bcur
__global__ __launch_bounds__(512) void k_bscan(const int* __restrict__ bcnt,
                                               int* __restrict__ boffs,
                                               int* __restrict__ bcur) {
    __shared__ int sh[512];
    int t = threadIdx.x;
    int v = t < NB ? bcnt[t] : 0;
    sh[t] = v;
    __syncthreads();
    #pragma unroll
    for (int d = 1; d < 512; d <<= 1) {
        int val = (t >= d) ? sh[t - d] : 0;
        __syncthreads();
        sh[t] += val;
        __syncthreads();
    }
    int excl = sh[t] - v;
    if (t < NB) { boffs[t] = excl; bcur[t] = excl; }
    if (t == NB - 1) boffs[NB] = excl + v;
}

// P1: scatter (src,dst) pairs into bucket-grouped order. Chunk = 2048 edges/block.
#define P1_EPT 8
__global__ __launch_bounds__(256) void k_bscatter(const int* __restrict__ src,
                                                  const int* __restrict__ dst,
                                                  int* __restrict__ bcur,
                                                  int2* __restrict__ pairs, int E) {
    __shared__ int h[NB];
    __shared__ int base[NB];
    int t = threadIdx.x;
    long long c0 = (long long)blockIdx.x * 2048;
    if (c0 >= E) return;
    for (int i = t; i < NB; i += 256) h[i] = 0;
    __syncthreads();
    int myb[P1_EPT], mylp[P1_EPT], mys[P1_EPT], myd[P1_EPT];
    #pragma unroll
    for (int k = 0; k < P1_EPT; ++k) {
        long long e = c0 + t + k * 256;
        if (e < E) {
            int d = dst[e];
            myd[k] = d; mys[k] = src[e];
            myb[k] = d >> BSHIFT;
            mylp[k] = atomicAdd(&h[myb[k]], 1);
        } else myb[k] = -1;
    }
    __syncthreads();
    for (int i = t; i < NB; i += 256)
        base[i] = h[i] ? atomicAdd(&bcur[i], h[i]) : 0;
    __syncthreads();
    #pragma unroll
    for (int k = 0; k < P1_EPT; ++k)
        if (myb[k] >= 0) pairs[base[myb[k]] + mylp[k]] = make_int2(mys[k], myd[k]);
}

// P2: per-bucket node in-degree histogram (LDS atomics only)
__global__ __launch_bounds__(256) void k_nodecnt(const int2* __restrict__ pairs,
                                                 const int* __restrict__ boffs,
                                                 int* __restrict__ cnt, int N) {
    __shared__ int h[BRANGE];
    int b = blockIdx.x, t = threadIdx.x;
    h[t] = 0;
    __syncthreads();
    int p0 = boffs[b], p1 = boffs[b + 1];
    for (int p = p0 + t; p < p1; p += 256)
        atomicAdd(&h[pairs[p].y & (BRANGE - 1)], 1);
    __syncthreads();
    int node = (b << BSHIFT) + t;
    if (node < N) cnt[node] = h[t];
}

// P4: per-bucket CSR scatter with LDS cursors
__global__ __launch_bounds__(256) void k_csr(const int2* __restrict__ pairs,
                                             const int* __restrict__ boffs,
                                             const int* __restrict__ offs,
                                             int* __restrict__ csr, int N) {
    __shared__ int cur[BRANGE];
    int b = blockIdx.x, t = threadIdx.x;
    int node = (b << BSHIFT) + t;
    cur[t] = node < N ? offs[node] : 0;
    __syncthreads();
    int p0 = boffs[b], p1 = boffs[b + 1];
    for (int p = p0 + t; p < p1; p += 256) {
        int2 pr = pairs[p];
        int pos = atomicAdd(&cur[pr.y & (BRANGE - 1)], 1);
        csr[pos] = pr.x;
    }
}

// ---------------- node-count exclusive scan ----------------

__global__ __launch_bounds__(256) void k_scan_local(const int* __restrict__ cnt,
                                                    int* __restrict__ offs,
                                                    int* __restrict__ bsums, int n) {
    __shared__ int sh[256];
    int t = threadIdx.x;
    int base = blockIdx.x * 1024 + t * 4;
    int v0 = base + 0 < n ? cnt[base + 0] : 0;
    int v1 = base + 1 < n ? cnt[base + 1] : 0;
    int v2 = base + 2 < n ? cnt[base + 2] : 0;
    int v3 = base + 3 < n ? cnt[base + 3] : 0;
    int tsum = v0 + v1 + v2 + v3;
    sh[t] = tsum;
    __syncthreads();
    #pragma unroll
    for (int d = 1; d < 256; d <<= 1) {
        int val = (t >= d) ? sh[t - d] : 0;
        __syncthreads();
        sh[t] += val;
        __syncthreads();
    }
    int excl = sh[t] - tsum;
    if (t == 255) bsums[blockIdx.x] = sh[255];
    if (base + 0 < n) offs[base + 0] = excl;
    if (base + 1 < n) offs[base + 1] = excl + v0;
    if (base + 2 < n) offs[base + 2] = excl + v0 + v1;
    if (base + 3 < n) offs[base + 3] = excl + v0 + v1 + v2;
}

__global__ __launch_bounds__(256) void k_scan_bsums(int* bsums, int nb) {
    __shared__ int sh[256];
    int t = threadIdx.x;
    int v = t < nb ? bsums[t] : 0;
    sh[t] = v;
    __syncthreads();
    #pragma unroll
    for (int d = 1; d < 256; d <<= 1) {
        int val = (t >= d) ? sh[t - d] : 0;
        __syncthreads();
        sh[t] += val;
        __syncthreads();
    }
    if (t < nb) bsums[t] = sh[t] - v;
}

__global__ void k_scan_add(int* __restrict__ offs, const int* __restrict__ bsums, int n) {
    int i = blockIdx.x * blockDim.x + threadIdx.x;
    if (i < n) offs[i] += bsums[i >> 10];
    if (i == 0) offs[n] = NEDGES;
}

// ---------------- MFMA GEMM: Y_bf16[n,128] = X_f32[n,128] @ W_f32[128,128] ----------------

__global__ __launch_bounds__(256) void k_gemm_mfma(const float* __restrict__ X,
                                                   const float* __restrict__ W,
                                                   ushort* __restrict__ Y, int nrows) {
    __shared__ short8v sW[2048];  // [kk(4)][ct(8)][lane(64)] -> 8 bf16
    const int tid = threadIdx.x;
    const int lane = tid & 63;
    const int w = tid >> 6;

    for (int s = tid; s < 2048; s += 256) {
        int p = s >> 6, l = s & 63;
        int kk = p >> 3, ct = p & 7;
        int kb = kk * 32 + (l >> 4) * 8;
        int j = ct * 16 + (l & 15);
        short8v v;
        #pragma unroll
        for (int i = 0; i < 8; ++i)
            v[i] = (short)f2bf(W[(size_t)(kb + i) * 128 + j]);
        sW[s] = v;
    }
    __syncthreads();

    const int row0 = blockIdx.x * 64 + w * 16;
    const int arow = row0 + (lane & 15);
    float4v acc[8];
    #pragma unroll
    for (int ct = 0; ct < 8; ++ct) acc[ct] = (float4v)0.f;

    #pragma unroll
    for (int kk = 0; kk < 4; ++kk) {
        short8v a = (short8v)0;
        if (arow < nrows) {
            const float* xp = X + (size_t)arow * 128 + kk * 32 + ((lane >> 4) * 8);
            float4 f0 = ((const float4*)xp)[0];
            float4 f1 = ((const float4*)xp)[1];
            a[0] = (short)f2bf(f0.x); a[1] = (short)f2bf(f0.y);
            a[2] = (short)f2bf(f0.z); a[3] = (short)f2bf(f0.w);
            a[4] = (short)f2bf(f1.x); a[5] = (short)f2bf(f1.y);
            a[6] = (short)f2bf(f1.z); a[7] = (short)f2bf(f1.w);
        }
        #pragma unroll
        for (int ct = 0; ct < 8; ++ct)
            acc[ct] = __builtin_amdgcn_mfma_f32_16x16x32_bf16(a, sW[(kk * 8 + ct) * 64 + lane],
                                                              acc[ct], 0, 0, 0);
    }

    const int orow = row0 + ((lane >> 4) << 2);
    #pragma unroll
    for (int r = 0; r < 4; ++r) {
        int row = orow + r;
        if (row < nrows) {
            #pragma unroll
            for (int ct = 0; ct < 8; ++ct)
                Y[(size_t)row * 128 + ct * 16 + (lane & 15)] = f2bf(acc[ct][r]);
        }
    }
}

// ---------------- CSR aggregation on bf16 messages ----------------

__global__ __launch_bounds__(256) void k_agg_bf16(const uint* __restrict__ xw,
                                                  const float* __restrict__ dinv,
                                                  const int* __restrict__ offs,
                                                  const int* __restrict__ csr,
                                                  const float* __restrict__ bias,
                                                  float2* __restrict__ out, int n, int dorelu) {
    int wid = (int)((blockIdx.x * 256 + threadIdx.x) >> 6);
    int lane = threadIdx.x & 63;
    if (wid >= n) return;
    float dd = dinv[wid];
    uint u = xw[(size_t)wid * 64 + lane];
    float sl = dd * dd;
    float ax = bflo(u) * sl, ay = bfhi(u) * sl;
    int e0 = offs[wid], e1 = offs[wid + 1];
    for (int e = e0; e < e1; e += 64) {
        int me = e + lane;
        int sidx = 0; float nr = 0.f;
        if (me < e1) { sidx = csr[me]; nr = dinv[sidx] * dd; }
        int cnt = min(64, e1 - e);
        int k = 0;
        for (; k + 2 <= cnt; k += 2) {
            int s0 = __shfl(sidx, k), s1 = __shfl(sidx, k + 1);
            float n0 = __shfl(nr, k), n1 = __shfl(nr, k + 1);
            uint u0 = xw[(size_t)s0 * 64 + lane];
            uint u1 = xw[(size_t)s1 * 64 + lane];
            ax += bflo(u0) * n0 + bflo(u1) * n1;
            ay += bfhi(u0) * n0 + bfhi(u1) * n1;
        }
        if (k < cnt) {
            int s0 = __shfl(sidx, k);
            float n0 = __shfl(nr, k);
            uint u0 = xw[(size_t)s0 * 64 + lane];
            ax += bflo(u0) * n0;
            ay += bfhi(u0) * n0;
        }
    }
    if (bias) {
        ax += bias[lane * 2];
        ay += bias[lane * 2 + 1];
        if (dorelu) { ax = fmaxf(ax, 0.f); ay = fmaxf(ay, 0.f); }
    }
    out[(size_t)wid * 64 + lane] = make_float2(ax, ay);
}

// ---------------- pooling ----------------

__global__ void k_bounds(const int* __restrict__ batch, int* __restrict__ start,
                         int* __restrict__ endx, int n) {
    int i = blockIdx.x * blockDim.x + threadIdx.x;
    if (i >= n) return;
    int b = batch[i];
    if (i == 0 || batch[i - 1] != b) start[b] = i;
    if (i == n - 1 || batch[i + 1] != b) endx[b] = i + 1;
}

__global__ __launch_bounds__(128) void k_pool_seg(const float* __restrict__ buf,
                                                  const int* __restrict__ start,
                                                  const int* __restrict__ endx,
                                                  float* __restrict__ sums) {
    int g = blockIdx.x;
    int chunk = blockIdx.y;
    int s = start[g], e = endx[g];
    int per = (e - s + 7) >> 3;
    int r0 = s + chunk * per;
    int r1 = min(e, r0 + per);
    int c = threadIdx.x;
    float acc = 0.f;
    for (int r = r0; r < r1; ++r) acc += buf[(size_t)r * 128 + c];
    atomicAdd(&sums[g * 128 + c], acc);
}

__global__ void k_final(const float* __restrict__ sums, const int* __restrict__ start,
                        const int* __restrict__ endx, const float* __restrict__ b2,
                        const float* __restrict__ linW, const float* __restrict__ linb,
                        float* __restrict__ out) {
    int tid = threadIdx.x;  // 512 = 64 graphs * 8 classes
    int g = tid >> 3, k = tid & 7;
    float cnt = (float)(endx[g] - start[g]);
    float inv = 1.0f / fmaxf(cnt, 1.0f);
    float acc = 0.f;
    for (int c = 0; c < 128; ++c)
        acc += (sums[(size_t)g * 128 + c] * inv + b2[c]) * linW[(size_t)c * 8 + k];
    out[(size_t)g * 8 + k] = acc + linb[k];
}

// ---------------- launch ----------------

extern "C" void kernel_launch(void* const* d_in, const int* in_sizes, int n_in,
                              void* d_out, int out_size, void* d_ws, size_t ws_size,
                              hipStream_t stream) {
    const float* x     = (const float*)d_in[0];
    const int*   ei    = (const int*)d_in[1];  // [2,E]: src = ei, dst = ei+E
    const int*   batch = (const int*)d_in[2];
    const float* W1    = (const float*)d_in[3];
    const float* b1    = (const float*)d_in[4];
    const float* W2    = (const float*)d_in[5];
    const float* b2    = (const float*)d_in[6];
    const float* linW  = (const float*)d_in[7];
    const float* linb  = (const float*)d_in[8];
    float* out = (float*)d_out;

    const int N = NNODES, E = NEDGES;
    const int* src = ei;
    const int* dst = ei + E;

    char* ws = (char*)d_ws;
    float* bufB   = (float*)ws;    ws += (size_t)N * 128 * 4;  // f32 hidden, 51.2MB
    uint*  bufA16 = (uint*)ws;     ws += (size_t)N * 64 * 4;   // bf16 xw, 25.6MB
    float* dinv   = (float*)ws;    ws += (size_t)N * 4;
    int*   cnt    = (int*)ws;      ws += (size_t)N * 4;
    int*   offs   = (int*)ws;      ws += (size_t)(N + 1) * 4;
    int*   bsums  = (int*)ws;      ws += 128 * 4;
    int*   csr    = (int*)ws;      ws += (size_t)E * 4;        // 6.4MB
    int*   bcnt   = (int*)ws;      ws += (NB + 1) * 4;
    int*   boffs  = (int*)ws;      ws += (NB + 1) * 4;
    int*   bcur   = (int*)ws;      ws += (NB + 1) * 4;
    float* sums   = (float*)ws;    ws += NGRAPHS * 128 * 4;
    int*   gstart = (int*)ws;      ws += NGRAPHS * 4;
    int*   gend   = (int*)ws;      ws += NGRAPHS * 4;
    // pairs buffer aliases bufB: CSR build finishes before agg1 writes bufB
    int2*  pairs  = (int2*)bufB;   // 12.8MB < 51.2MB

    const int B = 256;
    const int nScanBlocks = (N + 1023) / 1024;

    k_zero_int<<<(NB + B) / B, B, 0, stream>>>(bcnt, NB);
    k_zero_int<<<(NGRAPHS * 128 + 2 * NGRAPHS + B - 1) / B, B, 0, stream>>>((int*)sums,
                                                            NGRAPHS * 128 + 2 * NGRAPHS);

    // CSR build (bucketed, LDS-aggregated)
    k_bcount<<<256, B, 0, stream>>>(dst, bcnt, E);
    k_bscan<<<1, 512, 0, stream>>>(bcnt, boffs, bcur);
    k_bscatter<<<(E + 2047) / 2048, B, 0, stream>>>(src, dst, bcur, pairs, E);
    k_nodecnt<<<NB, B, 0, stream>>>(pairs, boffs, cnt, N);
    k_dinv<<<(N + B - 1) / B, B, 0, stream>>>(cnt, dinv, N);
    k_scan_local<<<nScanBlocks, B, 0, stream>>>(cnt, offs, bsums, N);
    k_scan_bsums<<<1, B, 0, stream>>>(bsums, nScanBlocks);
    k_scan_add<<<(N + B - 1) / B, B, 0, stream>>>(offs, bsums, N);
    k_csr<<<NB, B, 0, stream>>>(pairs, boffs, offs, csr, N);

    k_bounds<<<(N + B - 1) / B, B, 0, stream>>>(batch, gstart, gend, N);

    const int gemmGrid = (N + 63) / 64;
    const int aggGrid = (N * 64 + B - 1) / B;

    // layer 1
    k_gemm_mfma<<<gemmGrid, B, 0, stream>>>(x, W1, (ushort*)bufA16, N);
    k_agg_bf16<<<aggGrid, B, 0, stream>>>(bufA16, dinv, offs, csr, b1, (float2*)bufB, N, 1);

    // layer 2
    k_gemm_mfma<<<gemmGrid, B, 0, stream>>>(bufB, W2, (ushort*)bufA16, N);
    k_agg_bf16<<<aggGrid, B, 0, stream>>>(bufA16, dinv, offs, csr, nullptr, (float2*)bufB, N, 0);

    // pool + head
    k_pool_seg<<<dim3(NGRAPHS, 8), 128, 0, stream>>>(bufB, gstart, gend, sums);
    k_final<<<1, 512, 0, stream>>>(sums, gstart, gend, b2, linW, linb, out);
}

// Round 5
// 315.703 us; speedup vs baseline: 20.2699x; 1.1269x over previous
//
#include <hip/hip_runtime.h>
#include <cstdint>
#include <cstddef>

#define NNODES 100000
#define NEDGES 1600000
#define NGRAPHS 64
#define BSHIFT 8
#define BRANGE 256
#define NB 391  // ceil(NNODES / 256)

typedef short short8v __attribute__((ext_vector_type(8)));
typedef float float4v __attribute__((ext_vector_type(4)));

__device__ inline ushort f2bf(float f) {
    uint u = __float_as_uint(f);
    return (ushort)((u + 0x7fffu + ((u >> 16) & 1u)) >> 16);
}
__device__ inline uint pack2(float lo, float hi) {
    return (uint)f2bf(lo) | ((uint)f2bf(hi) << 16);
}
__device__ inline float bflo(uint u) { return __uint_as_float(u << 16); }
__device__ inline float bfhi(uint u) { return __uint_as_float(u & 0xffff0000u); }

// ---------------- utils ----------------

__global__ void k_zero_int(int* p, int n) {
    int i = blockIdx.x * blockDim.x + threadIdx.x;
    if (i < n) p[i] = 0;
}

// ---------------- CSR build (bucketed, LDS-aggregated) ----------------

__global__ __launch_bounds__(256) void k_bcount(const int* __restrict__ dst,
                                                int* __restrict__ bcnt, int E) {
    __shared__ int h[NB];
    for (int i = threadIdx.x; i < NB; i += 256) h[i] = 0;
    __syncthreads();
    for (int e = blockIdx.x * 256 + threadIdx.x; e < E; e += gridDim.x * 256)
        atomicAdd(&h[dst[e] >> BSHIFT], 1);
    __syncthreads();
    for (int i = threadIdx.x; i < NB; i += 256)
        if (h[i]) atomicAdd(&bcnt[i], h[i]);
}

__global__ __launch_bounds__(512) void k_bscan(const int* __restrict__ bcnt,
                                               int* __restrict__ boffs,
                                               int* __restrict__ bcur) {
    __shared__ int sh[512];
    int t = threadIdx.x;
    int v = t < NB ? bcnt[t] : 0;
    sh[t] = v;
    __syncthreads();
    #pragma unroll
    for (int d = 1; d < 512; d <<= 1) {
        int val = (t >= d) ? sh[t - d] : 0;
        __syncthreads();
        sh[t] += val;
        __syncthreads();
    }
    int excl = sh[t] - v;
    if (t < NB) { boffs[t] = excl; bcur[t] = excl; }
    if (t == NB - 1) boffs[NB] = excl + v;
}

#define P1_EPT 8
__global__ __launch_bounds__(256) void k_bscatter(const int* __restrict__ src,
                                                  const int* __restrict__ dst,
                                                  int* __restrict__ bcur,
                                                  int2* __restrict__ pairs, int E) {
    __shared__ int h[NB];
    __shared__ int base[NB];
    int t = threadIdx.x;
    long long c0 = (long long)blockIdx.x * 2048;
    if (c0 >= E) return;
    for (int i = t; i < NB; i += 256) h[i] = 0;
    __syncthreads();
    int myb[P1_EPT], mylp[P1_EPT], mys[P1_EPT], myd[P1_EPT];
    #pragma unroll
    for (int k = 0; k < P1_EPT; ++k) {
        long long e = c0 + t + k * 256;
        if (e < E) {
            int d = dst[e];
            myd[k] = d; mys[k] = src[e];
            myb[k] = d >> BSHIFT;
            mylp[k] = atomicAdd(&h[myb[k]], 1);
        } else myb[k] = -1;
    }
    __syncthreads();
    for (int i = t; i < NB; i += 256)
        base[i] = h[i] ? atomicAdd(&bcur[i], h[i]) : 0;
    __syncthreads();
    #pragma unroll
    for (int k = 0; k < P1_EPT; ++k)
        if (myb[k] >= 0) pairs[base[myb[k]] + mylp[k]] = make_int2(mys[k], myd[k]);
}

// per-bucket node in-degree histogram + dinv (fused)
__global__ __launch_bounds__(256) void k_nodecnt(const int2* __restrict__ pairs,
                                                 const int* __restrict__ boffs,
                                                 int* __restrict__ cnt,
                                                 float* __restrict__ dinv, int N) {
    __shared__ int h[BRANGE];
    int b = blockIdx.x, t = threadIdx.x;
    h[t] = 0;
    __syncthreads();
    int p0 = boffs[b], p1 = boffs[b + 1];
    for (int p = p0 + t; p < p1; p += 256)
        atomicAdd(&h[pairs[p].y & (BRANGE - 1)], 1);
    __syncthreads();
    int node = (b << BSHIFT) + t;
    if (node < N) {
        cnt[node] = h[t];
        dinv[node] = rsqrtf((float)(h[t] + 1));
    }
}

__global__ __launch_bounds__(256) void k_csr(const int2* __restrict__ pairs,
                                             const int* __restrict__ boffs,
                                             const int* __restrict__ offs,
                                             int* __restrict__ csr, int N) {
    __shared__ int cur[BRANGE];
    int b = blockIdx.x, t = threadIdx.x;
    int node = (b << BSHIFT) + t;
    cur[t] = node < N ? offs[node] : 0;
    __syncthreads();
    int p0 = boffs[b], p1 = boffs[b + 1];
    for (int p = p0 + t; p < p1; p += 256) {
        int2 pr = pairs[p];
        int pos = atomicAdd(&cur[pr.y & (BRANGE - 1)], 1);
        csr[pos] = pr.x;
    }
}

// ---------------- node-count exclusive scan ----------------

__global__ __launch_bounds__(256) void k_scan_local(const int* __restrict__ cnt,
                                                    int* __restrict__ offs,
                                                    int* __restrict__ bsums, int n) {
    __shared__ int sh[256];
    int t = threadIdx.x;
    int base = blockIdx.x * 1024 + t * 4;
    int v0 = base + 0 < n ? cnt[base + 0] : 0;
    int v1 = base + 1 < n ? cnt[base + 1] : 0;
    int v2 = base + 2 < n ? cnt[base + 2] : 0;
    int v3 = base + 3 < n ? cnt[base + 3] : 0;
    int tsum = v0 + v1 + v2 + v3;
    sh[t] = tsum;
    __syncthreads();
    #pragma unroll
    for (int d = 1; d < 256; d <<= 1) {
        int val = (t >= d) ? sh[t - d] : 0;
        __syncthreads();
        sh[t] += val;
        __syncthreads();
    }
    int excl = sh[t] - tsum;
    if (t == 255) bsums[blockIdx.x] = sh[255];
    if (base + 0 < n) offs[base + 0] = excl;
    if (base + 1 < n) offs[base + 1] = excl + v0;
    if (base + 2 < n) offs[base + 2] = excl + v0 + v1;
    if (base + 3 < n) offs[base + 3] = excl + v0 + v1 + v2;
}

__global__ __launch_bounds__(256) void k_scan_bsums(int* bsums, int nb) {
    __shared__ int sh[256];
    int t = threadIdx.x;
    int v = t < nb ? bsums[t] : 0;
    sh[t] = v;
    __syncthreads();
    #pragma unroll
    for (int d = 1; d < 256; d <<= 1) {
        int val = (t >= d) ? sh[t - d] : 0;
        __syncthreads();
        sh[t] += val;
        __syncthreads();
    }
    if (t < nb) bsums[t] = sh[t] - v;
}

// scan finalize + graph segment bounds (fused)
__global__ void k_scan_add_bounds(int* __restrict__ offs, const int* __restrict__ bsums,
                                  const int* __restrict__ batch, int* __restrict__ gstart,
                                  int* __restrict__ gend, int n) {
    int i = blockIdx.x * blockDim.x + threadIdx.x;
    if (i < n) {
        offs[i] += bsums[i >> 10];
        int b = batch[i];
        if (i == 0 || batch[i - 1] != b) gstart[b] = i;
        if (i == n - 1 || batch[i + 1] != b) gend[b] = i + 1;
    }
    if (i == 0) offs[n] = NEDGES;
}

// ---------------- MFMA GEMM: msg_bf16[n,128] = (X[n,128] @ W[128,128]) * dinv[row] ----------------
// f32-input variant (layer 1)

__global__ __launch_bounds__(256) void k_gemm_f32(const float* __restrict__ X,
                                                  const float* __restrict__ W,
                                                  const float* __restrict__ dinv,
                                                  ushort* __restrict__ Y, int nrows) {
    __shared__ short8v sW[2048];  // [kk(4)][ct(8)][lane(64)]
    const int tid = threadIdx.x;
    const int lane = tid & 63;
    const int w = tid >> 6;

    for (int s = tid; s < 2048; s += 256) {
        int p = s >> 6, l = s & 63;
        int kk = p >> 3, ct = p & 7;
        int kb = kk * 32 + (l >> 4) * 8;
        int j = ct * 16 + (l & 15);
        short8v v;
        #pragma unroll
        for (int i = 0; i < 8; ++i)
            v[i] = (short)f2bf(W[(size_t)(kb + i) * 128 + j]);
        sW[s] = v;
    }
    __syncthreads();

    const int row0 = blockIdx.x * 64 + w * 16;
    const int arow = row0 + (lane & 15);
    float4v acc[8];
    #pragma unroll
    for (int ct = 0; ct < 8; ++ct) acc[ct] = (float4v)0.f;

    #pragma unroll
    for (int kk = 0; kk < 4; ++kk) {
        short8v a = (short8v)0;
        if (arow < nrows) {
            const float* xp = X + (size_t)arow * 128 + kk * 32 + ((lane >> 4) * 8);
            float4 f0 = ((const float4*)xp)[0];
            float4 f1 = ((const float4*)xp)[1];
            a[0] = (short)f2bf(f0.x); a[1] = (short)f2bf(f0.y);
            a[2] = (short)f2bf(f0.z); a[3] = (short)f2bf(f0.w);
            a[4] = (short)f2bf(f1.x); a[5] = (short)f2bf(f1.y);
            a[6] = (short)f2bf(f1.z); a[7] = (short)f2bf(f1.w);
        }
        #pragma unroll
        for (int ct = 0; ct < 8; ++ct)
            acc[ct] = __builtin_amdgcn_mfma_f32_16x16x32_bf16(a, sW[(kk * 8 + ct) * 64 + lane],
                                                              acc[ct], 0, 0, 0);
    }

    const int orow = row0 + ((lane >> 4) << 2);
    #pragma unroll
    for (int r = 0; r < 4; ++r) {
        int row = orow + r;
        if (row < nrows) {
            float dr = dinv[row];
            #pragma unroll
            for (int ct = 0; ct < 8; ++ct)
                Y[(size_t)row * 128 + ct * 16 + (lane & 15)] = f2bf(acc[ct][r] * dr);
        }
    }
}

// bf16-input variant (layer 2): A fragments load directly, no conversion
__global__ __launch_bounds__(256) void k_gemm_b16(const ushort* __restrict__ X,
                                                  const float* __restrict__ W,
                                                  const float* __restrict__ dinv,
                                                  ushort* __restrict__ Y, int nrows) {
    __shared__ short8v sW[2048];
    const int tid = threadIdx.x;
    const int lane = tid & 63;
    const int w = tid >> 6;

    for (int s = tid; s < 2048; s += 256) {
        int p = s >> 6, l = s & 63;
        int kk = p >> 3, ct = p & 7;
        int kb = kk * 32 + (l >> 4) * 8;
        int j = ct * 16 + (l & 15);
        short8v v;
        #pragma unroll
        for (int i = 0; i < 8; ++i)
            v[i] = (short)f2bf(W[(size_t)(kb + i) * 128 + j]);
        sW[s] = v;
    }
    __syncthreads();

    const int row0 = blockIdx.x * 64 + w * 16;
    const int arow = row0 + (lane & 15);
    float4v acc[8];
    #pragma unroll
    for (int ct = 0; ct < 8; ++ct) acc[ct] = (float4v)0.f;

    #pragma unroll
    for (int kk = 0; kk < 4; ++kk) {
        short8v a = (short8v)0;
        if (arow < nrows)
            a = *(const short8v*)(X + (size_t)arow * 128 + kk * 32 + ((lane >> 4) * 8));
        #pragma unroll
        for (int ct = 0; ct < 8; ++ct)
            acc[ct] = __builtin_amdgcn_mfma_f32_16x16x32_bf16(a, sW[(kk * 8 + ct) * 64 + lane],
                                                              acc[ct], 0, 0, 0);
    }

    const int orow = row0 + ((lane >> 4) << 2);
    #pragma unroll
    for (int r = 0; r < 4; ++r) {
        int row = orow + r;
        if (row < nrows) {
            float dr = dinv[row];
            #pragma unroll
            for (int ct = 0; ct < 8; ++ct)
                Y[(size_t)row * 128 + ct * 16 + (lane & 15)] = f2bf(acc[ct][r] * dr);
        }
    }
}

// ---------------- CSR aggregation: wave/node, 16 lanes x 4 neighbors, uint4 gathers ----
// h[i,:] = relu( dinv[i] * (msg[i,:] + sum_{s in in(i)} msg[s,:]) + bias )

__global__ __launch_bounds__(256) void k_agg(const uint4* __restrict__ msg,
                                             const float* __restrict__ dinv,
                                             const int* __restrict__ offs,
                                             const int* __restrict__ csr,
                                             const float* __restrict__ bias,
                                             uint4* __restrict__ outb, int n, int dorelu) {
    int wid = (int)((blockIdx.x * 256 + threadIdx.x) >> 6);
    if (wid >= n) return;
    const int lane = threadIdx.x & 63;
    const int q = lane >> 4, c = lane & 15;
    float acc[8];
    {   // self contribution (weight 1) counted once, in q==0
        uint4 u = msg[(size_t)wid * 16 + c];
        float m = (q == 0) ? 1.f : 0.f;
        acc[0] = bflo(u.x) * m; acc[1] = bfhi(u.x) * m;
        acc[2] = bflo(u.y) * m; acc[3] = bfhi(u.y) * m;
        acc[4] = bflo(u.z) * m; acc[5] = bfhi(u.z) * m;
        acc[6] = bflo(u.w) * m; acc[7] = bfhi(u.w) * m;
    }
    const int e0 = offs[wid], e1 = offs[wid + 1];
    for (int base = e0; base < e1; base += 8) {
        int p0 = base + q, p1 = base + q + 4;
        int i0 = min(p0, e1 - 1), i1 = min(p1, e1 - 1);
        float m0 = (p0 < e1) ? 1.f : 0.f;
        float m1 = (p1 < e1) ? 1.f : 0.f;
        int s0 = csr[i0], s1 = csr[i1];
        uint4 u0 = msg[(size_t)s0 * 16 + c];
        uint4 u1 = msg[(size_t)s1 * 16 + c];
        acc[0] = fmaf(bflo(u0.x), m0, acc[0]);
        acc[1] = fmaf(bfhi(u0.x), m0, acc[1]);
        acc[2] = fmaf(bflo(u0.y), m0, acc[2]);
        acc[3] = fmaf(bfhi(u0.y), m0, acc[3]);
        acc[4] = fmaf(bflo(u0.z), m0, acc[4]);
        acc[5] = fmaf(bfhi(u0.z), m0, acc[5]);
        acc[6] = fmaf(bflo(u0.w), m0, acc[6]);
        acc[7] = fmaf(bfhi(u0.w), m0, acc[7]);
        acc[0] = fmaf(bflo(u1.x), m1, acc[0]);
        acc[1] = fmaf(bfhi(u1.x), m1, acc[1]);
        acc[2] = fmaf(bflo(u1.y), m1, acc[2]);
        acc[3] = fmaf(bfhi(u1.y), m1, acc[3]);
        acc[4] = fmaf(bflo(u1.z), m1, acc[4]);
        acc[5] = fmaf(bfhi(u1.z), m1, acc[5]);
        acc[6] = fmaf(bflo(u1.w), m1, acc[6]);
        acc[7] = fmaf(bfhi(u1.w), m1, acc[7]);
    }
    #pragma unroll
    for (int j = 0; j < 8; ++j) {
        acc[j] += __shfl_xor(acc[j], 16);
        acc[j] += __shfl_xor(acc[j], 32);
    }
    if (q == 0) {
        float dd = dinv[wid];
        #pragma unroll
        for (int j = 0; j < 8; ++j) {
            acc[j] *= dd;
            if (bias) acc[j] += bias[c * 8 + j];
            if (dorelu) acc[j] = fmaxf(acc[j], 0.f);
        }
        uint4 o;
        o.x = pack2(acc[0], acc[1]);
        o.y = pack2(acc[2], acc[3]);
        o.z = pack2(acc[4], acc[5]);
        o.w = pack2(acc[6], acc[7]);
        outb[(size_t)wid * 16 + c] = o;
    }
}

// ---------------- pooling (bf16 input) ----------------

__global__ __launch_bounds__(128) void k_pool16(const uint* __restrict__ buf,
                                                const int* __restrict__ gstart,
                                                const int* __restrict__ gend,
                                                float* __restrict__ sums) {
    int g = blockIdx.x, chunk = blockIdx.y;
    int s = gstart[g], e = gend[g];
    int per = (e - s + 7) >> 3;
    int r0 = s + chunk * per, r1 = min(e, r0 + per);
    int j = threadIdx.x & 63, half = threadIdx.x >> 6;
    float ax = 0.f, ay = 0.f;
    for (int r = r0 + half; r < r1; r += 2) {
        uint u = buf[(size_t)r * 64 + j];
        ax += bflo(u);
        ay += bfhi(u);
    }
    atomicAdd(&sums[g * 128 + 2 * j], ax);
    atomicAdd(&sums[g * 128 + 2 * j + 1], ay);
}

__global__ void k_final(const float* __restrict__ sums, const int* __restrict__ gstart,
                        const int* __restrict__ gend, const float* __restrict__ b2,
                        const float* __restrict__ linW, const float* __restrict__ linb,
                        float* __restrict__ out) {
    int tid = threadIdx.x;  // 512 = 64 graphs * 8 classes
    int g = tid >> 3, k = tid & 7;
    float cnt = (float)(gend[g] - gstart[g]);
    float inv = 1.0f / fmaxf(cnt, 1.0f);
    float acc = 0.f;
    for (int c = 0; c < 128; ++c)
        acc += (sums[(size_t)g * 128 + c] * inv + b2[c]) * linW[(size_t)c * 8 + k];
    out[(size_t)g * 8 + k] = acc + linb[k];
}

// ---------------- launch ----------------

extern "C" void kernel_launch(void* const* d_in, const int* in_sizes, int n_in,
                              void* d_out, int out_size, void* d_ws, size_t ws_size,
                              hipStream_t stream) {
    const float* x     = (const float*)d_in[0];
    const int*   ei    = (const int*)d_in[1];  // [2,E]: src = ei, dst = ei+E
    const int*   batch = (const int*)d_in[2];
    const float* W1    = (const float*)d_in[3];
    const float* b1    = (const float*)d_in[4];
    const float* W2    = (const float*)d_in[5];
    const float* b2    = (const float*)d_in[6];
    const float* linW  = (const float*)d_in[7];
    const float* linb  = (const float*)d_in[8];
    float* out = (float*)d_out;

    const int N = NNODES, E = NEDGES;
    const int* src = ei;
    const int* dst = ei + E;

    char* ws = (char*)d_ws;
    uint*  bufA16 = (uint*)ws;     ws += (size_t)N * 64 * 4;   // msg (bf16), 25.6MB
    uint*  bufH16 = (uint*)ws;     ws += (size_t)N * 64 * 4;   // h (bf16), 25.6MB
    float* dinv   = (float*)ws;    ws += (size_t)N * 4;
    int*   cnt    = (int*)ws;      ws += (size_t)N * 4;
    int*   offs   = (int*)ws;      ws += (size_t)(N + 1) * 4;
    int*   bsums  = (int*)ws;      ws += 128 * 4;
    int*   csr    = (int*)ws;      ws += (size_t)E * 4;        // 6.4MB
    int*   bcnt   = (int*)ws;      ws += (NB + 1) * 4;
    float* sums   = (float*)ws;    ws += NGRAPHS * 128 * 4;    // contiguous with bcnt (one zero)
    int*   boffs  = (int*)ws;      ws += (NB + 1) * 4;
    int*   bcur   = (int*)ws;      ws += (NB + 1) * 4;
    int*   gstart = (int*)ws;      ws += NGRAPHS * 4;
    int*   gend   = (int*)ws;      ws += NGRAPHS * 4;
    // pairs aliases bufH16: CSR build completes before agg1 writes h1
    int2*  pairs  = (int2*)bufH16;  // 12.8MB < 25.6MB

    const int B = 256;
    const int nScanBlocks = (N + 1023) / 1024;
    const int nzero = (NB + 1) + NGRAPHS * 128;

    k_zero_int<<<(nzero + B - 1) / B, B, 0, stream>>>(bcnt, nzero);

    // CSR build
    k_bcount<<<256, B, 0, stream>>>(dst, bcnt, E);
    k_bscan<<<1, 512, 0, stream>>>(bcnt, boffs, bcur);
    k_bscatter<<<(E + 2047) / 2048, B, 0, stream>>>(src, dst, bcur, pairs, E);
    k_nodecnt<<<NB, B, 0, stream>>>(pairs, boffs, cnt, dinv, N);
    k_scan_local<<<nScanBlocks, B, 0, stream>>>(cnt, offs, bsums, N);
    k_scan_bsums<<<1, B, 0, stream>>>(bsums, nScanBlocks);
    k_scan_add_bounds<<<(N + B - 1) / B, B, 0, stream>>>(offs, bsums, batch, gstart, gend, N);
    k_csr<<<NB, B, 0, stream>>>(pairs, boffs, offs, csr, N);

    const int gemmGrid = (N + 63) / 64;
    const int aggGrid = (N * 64 + B - 1) / B;

    // layer 1
    k_gemm_f32<<<gemmGrid, B, 0, stream>>>(x, W1, dinv, (ushort*)bufA16, N);
    k_agg<<<aggGrid, B, 0, stream>>>((const uint4*)bufA16, dinv, offs, csr, b1,
                                     (uint4*)bufH16, N, 1);

    // layer 2
    k_gemm_b16<<<gemmGrid, B, 0, stream>>>((const ushort*)bufH16, W2, dinv,
                                           (ushort*)bufA16, N);
    k_agg<<<aggGrid, B, 0, stream>>>((const uint4*)bufA16, dinv, offs, csr, nullptr,
                                     (uint4*)bufH16, N, 0);

    // pool + head
    k_pool16<<<dim3(NGRAPHS, 8), 128, 0, stream>>>(bufH16, gstart, gend, sums);
    k_final<<<1, 512, 0, stream>>>(sums, gstart, gend, b2, linW, linb, out);
}